// Round 1
// 785.461 us; speedup vs baseline: 1.1261x; 1.1261x over previous
//
#include <hip/hip_runtime.h>

#define DI __device__ __forceinline__

typedef __attribute__((ext_vector_type(8))) short s16x8;
typedef __attribute__((ext_vector_type(4))) float f32x4;

DI f32x4 mfma16(s16x8 a, s16x8 b, f32x4 c) {
  return __builtin_amdgcn_mfma_f32_16x16x32_bf16(a, b, c, 0, 0, 0);
}

DI unsigned short f2bf(float f) {
  unsigned int u = __builtin_bit_cast(unsigned int, f);
  u += 0x7fffu + ((u >> 16) & 1u);
  return (unsigned short)(u >> 16);
}
DI float bf2f(unsigned short h) {
  unsigned int u = ((unsigned int)h) << 16;
  return __builtin_bit_cast(float, u);
}
DI void split2(float f, unsigned short &hi, unsigned short &lo) {
  hi = f2bf(f);
  lo = f2bf(f - bf2f(hi));
}

// v_cvt_pk_bf16_f32: dst.lo = bf16_rne(s0), dst.hi = bf16_rne(s1) — same RNE
// rule as f2bf, so the bf16x3 decomposition below is bit-identical to split2.
DI unsigned int cvtpk(float a, float b) {
  unsigned int r;
  asm("v_cvt_pk_bf16_f32 %0, %1, %2" : "=v"(r) : "v"(a), "v"(b));
  return r;
}
DI float fromlo(unsigned int u) { return __builtin_bit_cast(float, u << 16); }
DI float fromhi(unsigned int u) { return __builtin_bit_cast(float, u & 0xffff0000u); }

// 8 contiguous elements -> hi row + lo row, one ds_write_b128 each (bank-uniform)
DI void write_pair8(unsigned short* hp, unsigned short* lp, float4 a, float4 b) {
  unsigned int h01 = cvtpk(a.x, a.y), h23 = cvtpk(a.z, a.w);
  unsigned int h45 = cvtpk(b.x, b.y), h67 = cvtpk(b.z, b.w);
  unsigned int l01 = cvtpk(a.x - fromlo(h01), a.y - fromhi(h01));
  unsigned int l23 = cvtpk(a.z - fromlo(h23), a.w - fromhi(h23));
  unsigned int l45 = cvtpk(b.x - fromlo(h45), b.y - fromhi(h45));
  unsigned int l67 = cvtpk(b.z - fromlo(h67), b.w - fromhi(h67));
  uint4 H4; H4.x = h01; H4.y = h23; H4.z = h45; H4.w = h67;
  uint4 L4; L4.x = l01; L4.y = l23; L4.z = l45; L4.w = l67;
  *(uint4*)hp = H4;
  *(uint4*)lp = L4;
}

// fast gates: v_exp_f32 + v_rcp_f32 (~3e-7 rel err; inside bf16x3 noise envelope)
DI float fsig(float x)  { return __builtin_amdgcn_rcpf(1.f + __expf(-x)); }
DI float ftanhf(float x){ return 1.f - 2.f * __builtin_amdgcn_rcpf(1.f + __expf(2.f * x)); }

// ---------------------------------------------------------------------------
// Split-K bf16x3 GEMM, 128x128 tiles, double-buffered LDS (1 barrier/iter).
// P[kidx][M][N] partials. Staging via cvt_pk + b128 stores; MFMA in 3 passes
// (hh / lh / hl) so each acc is revisited at distance 16 (dep-latency hidden).
// Accumulation order per acc is unchanged -> bit-exact vs previous version.
// ---------------------------------------------------------------------------
template<int M, int N, int K, int KS, bool SWZ>
__global__ __launch_bounds__(256, 2) void k_gemm(const float* __restrict__ A,
                                                 const float* __restrict__ Bw,
                                                 float* __restrict__ P) {
  constexpr int MT = M / 128, NT = N / 128;
  constexpr int KC = K / KS;
  constexpr int ITERS = KC / 32;
  int bid = blockIdx.x;
  int kidx, mt, nt;
  if (SWZ) {
    int xcd = bid & 7, s = bid >> 3;
    kidx = xcd + 8 * (s >> 4);
    int mn = s & 15; mt = mn >> 3; nt = mn & 7;
  } else {
    kidx = bid / (MT * NT);
    int mn = bid % (MT * NT);
    mt = mn / NT; nt = mn % NT;
  }
  int tid = threadIdx.x;
  int w = tid >> 6, lane = tid & 63, q = lane >> 4, l15 = lane & 15;
  int wm = w >> 1, wn = w & 1;

  __shared__ unsigned short Ah[2][4][128][8], Al[2][4][128][8];
  __shared__ unsigned short Bh[2][4][128][8], Bl[2][4][128][8];

  int srow = tid >> 1;
  int skb  = (tid & 1) * 16;
  const float* Abase = A  + (size_t)(mt * 128 + srow) * K + (size_t)kidx * KC;
  const float* Bbase = Bw + (size_t)(nt * 128 + srow) * K + (size_t)kidx * KC;

  float4 ra[4], rb[4];
  auto loadit = [&](int it) {
    const float* pa = Abase + it * 32 + skb;
    const float* pb = Bbase + it * 32 + skb;
#pragma unroll
    for (int i = 0; i < 4; i++) {
      ra[i] = *(const float4*)(pa + 4 * i);
      rb[i] = *(const float4*)(pb + 4 * i);
    }
  };
  auto stage = [&](int pb) {
    int qq0 = skb >> 3;  // 0 or 2
    write_pair8(&Ah[pb][qq0][srow][0],     &Al[pb][qq0][srow][0],     ra[0], ra[1]);
    write_pair8(&Ah[pb][qq0 + 1][srow][0], &Al[pb][qq0 + 1][srow][0], ra[2], ra[3]);
    write_pair8(&Bh[pb][qq0][srow][0],     &Bl[pb][qq0][srow][0],     rb[0], rb[1]);
    write_pair8(&Bh[pb][qq0 + 1][srow][0], &Bl[pb][qq0 + 1][srow][0], rb[2], rb[3]);
  };

  f32x4 acc[4][4];
#pragma unroll
  for (int i = 0; i < 4; i++)
#pragma unroll
    for (int j = 0; j < 4; j++) acc[i][j] = (f32x4){0.f, 0.f, 0.f, 0.f};

  loadit(0);
  stage(0);
  loadit(1);

  for (int it = 0; it < ITERS; ++it) {
    __syncthreads();
    if (it + 1 < ITERS) stage((it + 1) & 1);
    if (it + 2 < ITERS) loadit(it + 2);
    int pr = it & 1;

    s16x8 afh[4], afl[4], bfh[4], bfl[4];
#pragma unroll
    for (int t = 0; t < 4; t++) {
      int m = wm * 64 + 16 * t + l15;
      afh[t] = *(const s16x8*)&Ah[pr][q][m][0];
      afl[t] = *(const s16x8*)&Al[pr][q][m][0];
      int n = wn * 64 + 16 * t + l15;
      bfh[t] = *(const s16x8*)&Bh[pr][q][n][0];
      bfl[t] = *(const s16x8*)&Bl[pr][q][n][0];
    }
    // pass 1: hh
#pragma unroll
    for (int ti = 0; ti < 4; ti++)
#pragma unroll
      for (int tj = 0; tj < 4; tj++)
        acc[ti][tj] = mfma16(afh[ti], bfh[tj], acc[ti][tj]);
    // pass 2: lh
#pragma unroll
    for (int ti = 0; ti < 4; ti++)
#pragma unroll
      for (int tj = 0; tj < 4; tj++)
        acc[ti][tj] = mfma16(afl[ti], bfh[tj], acc[ti][tj]);
    // pass 3: hl
#pragma unroll
    for (int ti = 0; ti < 4; ti++)
#pragma unroll
      for (int tj = 0; tj < 4; tj++)
        acc[ti][tj] = mfma16(afh[ti], bfl[tj], acc[ti][tj]);
  }
#pragma unroll
  for (int ti = 0; ti < 4; ti++)
#pragma unroll
    for (int tj = 0; tj < 4; tj++)
#pragma unroll
      for (int r = 0; r < 4; r++) {
        int row = mt * 128 + wm * 64 + 16 * ti + 4 * q + r;
        int col = nt * 128 + wn * 64 + 16 * tj + l15;
        P[((size_t)kidx * M + row) * N + col] = acc[ti][tj][r];
      }
}

// ---------------------------------------------------------------------------
template<int KS>
__global__ __launch_bounds__(256) void k_red(const float* __restrict__ P,
                                             float* __restrict__ O) {
  int idx = blockIdx.x * 256 + threadIdx.x;
  float s = 0.f;
#pragma unroll
  for (int kk = 0; kk < KS; kk++) s += P[(size_t)kk * 262144 + idx];
  O[idx] = s;
}

// ---------------------------------------------------------------------------
template<int KS, int N>
__global__ __launch_bounds__(256) void k_bn(const float* __restrict__ P,
                                            const float* __restrict__ g,
                                            const float* __restrict__ be,
                                            float* __restrict__ a) {
  int tid = threadIdx.x;
  int c = tid & 15, bg = tid >> 4;
  int col = blockIdx.x * 16 + c;
  __shared__ float hbuf[256][16];
  __shared__ float sbuf[16][16], s2buf[16][16];
  __shared__ float msc[16], msh[16];
  float s = 0.f, s2 = 0.f;
  for (int b = bg * 16; b < bg * 16 + 16; b++) {
    float h = 0.f;
#pragma unroll
    for (int kk = 0; kk < KS; kk++) h += P[((size_t)kk * 256 + b) * N + col];
    hbuf[b][c] = h;
    s += h; s2 += h * h;
  }
  sbuf[bg][c] = s; s2buf[bg][c] = s2;
  __syncthreads();
  if (bg == 0) {
    float ts = 0.f, ts2 = 0.f;
#pragma unroll
    for (int i = 0; i < 16; i++) { ts += sbuf[i][c]; ts2 += s2buf[i][c]; }
    float m = ts * (1.f / 256.f);
    float v = ts2 * (1.f / 256.f) - m * m;
    float rs = rsqrtf(v + 1e-5f);
    float sc = g[col] * rs;
    msc[c] = sc;
    msh[c] = be[col] - m * sc;
  }
  __syncthreads();
  float sc = msc[c], sh = msh[c];
  for (int b = bg * 16; b < bg * 16 + 16; b++) {
    float v = hbuf[b][c] * sc + sh;
    a[(size_t)b * N + col] = v > 0.f ? v : 0.01f * v;
  }
}

// ---------------------------------------------------------------------------
__global__ __launch_bounds__(128) void k_head(const float* __restrict__ P3,
    const float* __restrict__ bout,
    const float* __restrict__ Wmu, const float* __restrict__ bmu,
    const float* __restrict__ Wlv, const float* __restrict__ blv,
    const float* __restrict__ Wih, const float* __restrict__ bih,
    const float* __restrict__ eps,
    float* __restrict__ out_mu, float* __restrict__ out_lv,
    float* __restrict__ xp) {
  int b = blockIdx.x, j = threadIdx.x;
  __shared__ float es[128], zs[128];
  float e = P3[(size_t)b * 128 + j] + P3[(size_t)(256 + b) * 128 + j] + bout[j];
  es[j] = e > 0.f ? e : 0.f;
  __syncthreads();
  float mu = bmu[j], lv = blv[j];
  for (int k = 0; k < 128; k++) {
    mu += es[k] * Wmu[j * 128 + k];
    lv += es[k] * Wlv[j * 128 + k];
  }
  out_mu[b * 128 + j] = mu;
  out_lv[b * 128 + j] = lv;
  float z = mu + eps[b * 128 + j] * expf(0.5f * lv);
  zs[j] = z;
  __syncthreads();
  for (int gi = 0; gi < 3; gi++) {
    int row = gi * 128 + j;
    float s = bih[row];
    for (int k = 0; k < 128; k++) s += zs[k] * Wih[row * 128 + k];
    xp[(size_t)b * 384 + row] = s;
  }
}

// ---------------------------------------------------------------------------
// GRU recurrence: 16 blocks x 16 batch, 512 threads (8 waves = 2 waves/SIMD
// for latency hiding; was 4 waves = 1/SIMD fully latency-exposed).
// Each wave owns 3 gate tiles (16 rows of r,z,n each); Whh bf16x3 frags
// resident in VGPRs (96 regs/wave); ping-pong h2 LDS; 9-slot LDS h ring ->
// one coalesced H burst per 8 steps. MFMA loop kt-outer so each acc is
// revisited at distance 9 (per-acc accumulation order unchanged -> bit-exact).
// h2 split via v_cvt_pk_bf16_f32 (RNE, identical to split2).
// ---------------------------------------------------------------------------
__global__ __launch_bounds__(512, 2) void k_gru(const float* __restrict__ Whh,
    const float* __restrict__ bhh, const float* __restrict__ xp,
    float* __restrict__ H) {
  int b0 = blockIdx.x * 16;
  int tid = threadIdx.x;
  int w = tid >> 6, lane = tid & 63, q = lane >> 4, l15 = lane & 15;
  __shared__ unsigned short h2hi[2][16][136], h2lo[2][16][136];
  __shared__ float hstage[9][16][132];
  (void)lane;

  int rb3[3];
  rb3[0] = 16 * w;        // r-gate rows
  rb3[1] = 128 + 16 * w;  // z-gate rows
  rb3[2] = 256 + 16 * w;  // n-gate rows

  // weight fragments (A-operand: m=l15 row-in-tile, k = kt*32 + q*8 + j)
  s16x8 wfh[3][4], wfl[3][4];
#pragma unroll
  for (int t = 0; t < 3; t++)
#pragma unroll
    for (int kt = 0; kt < 4; kt++) {
      const float* p = Whh + (size_t)(rb3[t] + l15) * 128 + kt * 32 + q * 8;
      s16x8 hi, lo;
#pragma unroll
      for (int j = 0; j < 8; j++) {
        unsigned short h, l; split2(p[j], h, l);
        hi[j] = (short)h; lo[j] = (short)l;
      }
      wfh[t][kt] = hi; wfl[t][kt] = lo;
    }

  int gb = b0 + l15;
  int k0 = 16 * w + 4 * q;  // this thread's hid base (+r)
  float xr_[4], xz_[4], xn_[4], bhn_[4], hprev[4];
#pragma unroll
  for (int r = 0; r < 4; r++) {
    int kk = k0 + r;
    xr_[r] = xp[(size_t)gb * 384 + kk] + bhh[kk];
    xz_[r] = xp[(size_t)gb * 384 + 128 + kk] + bhh[128 + kk];
    xn_[r] = xp[(size_t)gb * 384 + 256 + kk];
    bhn_[r] = bhh[256 + kk];
    hprev[r] = 0.f;
  }

  for (int i = tid; i < 16 * 136; i += 512) {
    (&h2hi[0][0][0])[i] = 0;
    (&h2lo[0][0][0])[i] = 0;
  }
  __syncthreads();

  int hrow = tid >> 5, hcol = (tid & 31) * 4;
  int sl = 0;  // == s % 9

  for (int s = 0; s < 128; s++) {
    int p = s & 1;
    // B-frags for step s (prev h2), issued first
    s16x8 bhf[4], blf[4];
#pragma unroll
    for (int kt = 0; kt < 4; kt++) {
      bhf[kt] = *(const s16x8*)&h2hi[p][l15][kt * 32 + q * 8];
      blf[kt] = *(const s16x8*)&h2lo[p][l15][kt * 32 + q * 8];
    }
    // burst-flush previous 8 steps' h (overlaps B-frag latency + MFMA)
    if ((s & 7) == 0 && s) {
      int fb = s - 8;
#pragma unroll
      for (int ss = 0; ss < 8; ss++) {
        int t9 = sl + 1 + ss;           // (fb+ss) % 9
        int fsl = t9 >= 9 ? t9 - 9 : t9;
        float4 v = *(const float4*)&hstage[fsl][hrow][hcol];
        *(float4*)(H + ((size_t)(b0 + hrow) * 128 + fb + ss) * 128 + hcol) = v;
      }
    }

    // 6 independent MFMA chains, kt-outer (acc revisit distance 9)
    f32x4 accm[3], accc[3];
#pragma unroll
    for (int t = 0; t < 3; t++) {
      accm[t] = (f32x4){0.f, 0.f, 0.f, 0.f};
      accc[t] = (f32x4){0.f, 0.f, 0.f, 0.f};
    }
#pragma unroll
    for (int kt = 0; kt < 4; kt++) {
#pragma unroll
      for (int t = 0; t < 3; t++) accm[t] = mfma16(wfh[t][kt], bhf[kt], accm[t]);
#pragma unroll
      for (int t = 0; t < 3; t++) accc[t] = mfma16(wfl[t][kt], bhf[kt], accc[t]);
#pragma unroll
      for (int t = 0; t < 3; t++) accc[t] = mfma16(wfh[t][kt], blf[kt], accc[t]);
    }

    float hv[4];
#pragma unroll
    for (int r = 0; r < 4; r++) {
      float hr = accm[0][r] + accc[0][r];
      float hz = accm[1][r] + accc[1][r];
      float hn = accm[2][r] + accc[2][r];
      float rg = fsig(xr_[r] + hr);
      float zg = fsig(xz_[r] + hz);
      float ng = ftanhf(fmaf(rg, hn + bhn_[r], xn_[r]));
      float h2 = fmaf(zg, hprev[r] - ng, ng);
      hprev[r] = h2;
      hv[r] = h2;
    }
    unsigned int h01 = cvtpk(hv[0], hv[1]), h23 = cvtpk(hv[2], hv[3]);
    unsigned int l01 = cvtpk(hv[0] - fromlo(h01), hv[1] - fromhi(h01));
    unsigned int l23 = cvtpk(hv[2] - fromlo(h23), hv[3] - fromhi(h23));
    *(float4*)&hstage[sl][l15][k0] = make_float4(hv[0], hv[1], hv[2], hv[3]);
    uint2 hh; hh.x = h01; hh.y = h23;
    uint2 ll; ll.x = l01; ll.y = l23;
    *(uint2*)&h2hi[p ^ 1][l15][k0] = hh;
    *(uint2*)&h2lo[p ^ 1][l15][k0] = ll;
    sl = (sl == 8) ? 0 : sl + 1;
    __syncthreads();
  }
  // final flush: steps 120..127
#pragma unroll
  for (int ss = 0; ss < 8; ss++) {
    int fb = 120 + ss;
    int fsl = fb % 9;
    float4 v = *(const float4*)&hstage[fsl][hrow][hcol];
    *(float4*)(H + ((size_t)(b0 + hrow) * 128 + fb) * 128 + hcol) = v;
  }
}

// ---------------------------------------------------------------------------
// Phase B: logits = H @ Wfc^T + bfc, argmax (first-index), one-hot
// ---------------------------------------------------------------------------
__global__ __launch_bounds__(256, 2) void k_fc(const float* __restrict__ H,
    const float* __restrict__ Wfc, const float* __restrict__ bfc,
    float* __restrict__ out) {
  int rows0 = blockIdx.x * 64;
  int tid = threadIdx.x;
  int w = tid >> 6, lane = tid & 63, q = lane >> 4, l15 = lane & 15;
  __shared__ unsigned short Ah[4][4][64][8], Al[4][4][64][8];
  __shared__ unsigned short Bh[4][4][32][8], Bl[4][4][32][8];
  __shared__ int argbuf[64];
  (void)lane;

  {
    int row = tid >> 2, kb = (tid & 3) * 32;
    const float* p = H + (size_t)(rows0 + row) * 128 + kb;
    int kt = kb >> 5;
    float4 v[8];
#pragma unroll
    for (int i = 0; i < 8; i++) v[i] = *(const float4*)(p + 4 * i);
#pragma unroll
    for (int j = 0; j < 4; j++)
      write_pair8(&Ah[kt][j][row][0], &Al[kt][j][row][0], v[2 * j], v[2 * j + 1]);
  }
  __syncthreads();

  s16x8 afh[4], afl[4];
#pragma unroll
  for (int kt = 0; kt < 4; kt++) {
    afh[kt] = *(const s16x8*)&Ah[kt][q][16 * w + l15][0];
    afl[kt] = *(const s16x8*)&Al[kt][q][16 * w + l15][0];
  }

  float best[4]; int bidx[4];
#pragma unroll
  for (int r = 0; r < 4; r++) { best[r] = -3.4e38f; bidx[r] = 0; }

  for (int c = 0; c < 16; c++) {
    {
      int n = tid >> 3, kb = (tid & 7) * 16;
      const float* p = Wfc + (size_t)(c * 32 + n) * 128 + kb;
      int kt = kb >> 5, qq0 = (kb >> 3) & 3;  // qq0 in {0,2}
      float4 v0 = *(const float4*)(p);
      float4 v1 = *(const float4*)(p + 4);
      float4 v2 = *(const float4*)(p + 8);
      float4 v3 = *(const float4*)(p + 12);
      write_pair8(&Bh[kt][qq0][n][0],     &Bl[kt][qq0][n][0],     v0, v1);
      write_pair8(&Bh[kt][qq0 + 1][n][0], &Bl[kt][qq0 + 1][n][0], v2, v3);
    }
    __syncthreads();
    f32x4 acc[2];
    acc[0] = (f32x4){0.f, 0.f, 0.f, 0.f};
    acc[1] = (f32x4){0.f, 0.f, 0.f, 0.f};
    s16x8 bh[2][4], bl[2][4];
#pragma unroll
    for (int nt = 0; nt < 2; nt++)
#pragma unroll
      for (int kt = 0; kt < 4; kt++) {
        bh[nt][kt] = *(const s16x8*)&Bh[kt][q][nt * 16 + l15][0];
        bl[nt][kt] = *(const s16x8*)&Bl[kt][q][nt * 16 + l15][0];
      }
#pragma unroll
    for (int kt = 0; kt < 4; kt++)
#pragma unroll
      for (int nt = 0; nt < 2; nt++) {
        acc[nt] = mfma16(afh[kt], bh[nt][kt], acc[nt]);
        acc[nt] = mfma16(afl[kt], bh[nt][kt], acc[nt]);
        acc[nt] = mfma16(afh[kt], bl[nt][kt], acc[nt]);
      }
#pragma unroll
    for (int nt = 0; nt < 2; nt++)
#pragma unroll
      for (int r = 0; r < 4; r++) {
        int col = c * 32 + nt * 16 + l15;
        float v = acc[nt][r] + bfc[col];
        if (v > best[r]) { best[r] = v; bidx[r] = col; }
      }
    __syncthreads();
  }

#pragma unroll
  for (int r = 0; r < 4; r++) {
    float bv = best[r]; int bi = bidx[r];
    for (int off = 8; off >= 1; off >>= 1) {
      float ov = __shfl_xor(bv, off, 64);
      int oi = __shfl_xor(bi, off, 64);
      if (ov > bv || (ov == bv && oi < bi)) { bv = ov; bi = oi; }
    }
    if (l15 == 0) argbuf[16 * w + 4 * q + r] = bi;
  }
  __syncthreads();

  int row = tid >> 2, cb = (tid & 3) * 128;
  int am = argbuf[row];
  float* op = out + (size_t)(rows0 + row) * 512 + cb;
#pragma unroll
  for (int i = 0; i < 32; i++) {
    float4 v = {0.f, 0.f, 0.f, 0.f};
    int base = cb + 4 * i;
    if (am >= base && am < base + 4) ((float*)&v)[am - base] = 1.0f;
    *(float4*)(op + 4 * i) = v;
  }
}

// ---------------------------------------------------------------------------
extern "C" void kernel_launch(void* const* d_in, const int* in_sizes, int n_in,
                              void* d_out, int out_size, void* d_ws, size_t ws_size,
                              hipStream_t stream) {
  const float* x    = (const float*)d_in[0];
  const float* eps  = (const float*)d_in[1];
  const float* W0   = (const float*)d_in[2];
  const float* g0   = (const float*)d_in[4];
  const float* be0  = (const float*)d_in[5];
  const float* W1   = (const float*)d_in[6];
  const float* g1   = (const float*)d_in[8];
  const float* be1  = (const float*)d_in[9];
  const float* W2   = (const float*)d_in[10];
  const float* g2   = (const float*)d_in[12];
  const float* be2  = (const float*)d_in[13];
  const float* Wout = (const float*)d_in[14];
  const float* bout = (const float*)d_in[15];
  const float* Wmu  = (const float*)d_in[16];
  const float* bmu  = (const float*)d_in[17];
  const float* Wlv  = (const float*)d_in[18];
  const float* blv  = (const float*)d_in[19];
  const float* Wih  = (const float*)d_in[20];
  const float* bih  = (const float*)d_in[21];
  const float* Whh  = (const float*)d_in[22];
  const float* bhh  = (const float*)d_in[23];
  const float* Wfc  = (const float*)d_in[24];
  const float* bfc  = (const float*)d_in[25];

  float* out    = (float*)d_out;
  float* mu_out = out + 16777216;
  float* lv_out = out + 16777216 + 32768;

  const bool big = ws_size >= 75900000ull;
  const int KS0 = big ? 64 : 16;

  float* ws  = (float*)d_ws;
  float* P0  = ws;
  float* O0  = ws + (size_t)262144 * KS0;
  float* a1  = O0 + 262144;
  float* P1  = a1 + 262144;
  float* a2  = P1 + 1048576;
  float* P2  = a2 + 131072;
  float* a3  = P2 + 262144;
  float* P3  = a3 + 65536;
  float* xp  = P3 + 65536;
  float* Hst = ws;  // aliases P0 (dead after k_red)

  if (big) {
    hipLaunchKernelGGL((k_gemm<256,1024,65536,64,true>), dim3(1024), dim3(256), 0, stream, x, W0, P0);
    hipLaunchKernelGGL((k_red<64>),                      dim3(1024), dim3(256), 0, stream, P0, O0);
  } else {
    hipLaunchKernelGGL((k_gemm<256,1024,65536,16,true>), dim3(256),  dim3(256), 0, stream, x, W0, P0);
    hipLaunchKernelGGL((k_red<16>),                      dim3(1024), dim3(256), 0, stream, P0, O0);
  }
  hipLaunchKernelGGL((k_bn<1,1024>),                   dim3(64),  dim3(256), 0, stream, O0, g0, be0, a1);
  hipLaunchKernelGGL((k_gemm<256,512,1024,8,false>),   dim3(64),  dim3(256), 0, stream, a1, W1, P1);
  hipLaunchKernelGGL((k_bn<8,512>),                    dim3(32),  dim3(256), 0, stream, P1, g1, be1, a2);
  hipLaunchKernelGGL((k_gemm<256,256,512,4,false>),    dim3(16),  dim3(256), 0, stream, a2, W2, P2);
  hipLaunchKernelGGL((k_bn<4,256>),                    dim3(16),  dim3(256), 0, stream, P2, g2, be2, a3);
  hipLaunchKernelGGL((k_gemm<256,128,256,2,false>),    dim3(4),   dim3(256), 0, stream, a3, Wout, P3);
  hipLaunchKernelGGL(k_head, dim3(256), dim3(128), 0, stream, P3, bout, Wmu, bmu, Wlv, blv, Wih, bih, eps, mu_out, lv_out, xp);
  hipLaunchKernelGGL(k_gru,  dim3(16),  dim3(512), 0, stream, Whh, bhh, xp, Hst);
  hipLaunchKernelGGL(k_fc,   dim3(512), dim3(256), 0, stream, Hst, Wfc, bfc, out);
}

// Round 2
// 783.431 us; speedup vs baseline: 1.1290x; 1.0026x over previous
//
#include <hip/hip_runtime.h>

#define DI __device__ __forceinline__

typedef __attribute__((ext_vector_type(8))) short s16x8;
typedef __attribute__((ext_vector_type(4))) float f32x4;

template<int I> struct Ic { static constexpr int value = I; };

DI f32x4 mfma16(s16x8 a, s16x8 b, f32x4 c) {
  return __builtin_amdgcn_mfma_f32_16x16x32_bf16(a, b, c, 0, 0, 0);
}

DI unsigned short f2bf(float f) {
  unsigned int u = __builtin_bit_cast(unsigned int, f);
  u += 0x7fffu + ((u >> 16) & 1u);
  return (unsigned short)(u >> 16);
}
DI float bf2f(unsigned short h) {
  unsigned int u = ((unsigned int)h) << 16;
  return __builtin_bit_cast(float, u);
}
DI void split2(float f, unsigned short &hi, unsigned short &lo) {
  hi = f2bf(f);
  lo = f2bf(f - bf2f(hi));
}

// v_cvt_pk_bf16_f32: dst.lo = bf16_rne(s0), dst.hi = bf16_rne(s1) — same RNE
// rule as f2bf, so the bf16x3 decomposition below is bit-identical to split2.
DI unsigned int cvtpk(float a, float b) {
  unsigned int r;
  asm("v_cvt_pk_bf16_f32 %0, %1, %2" : "=v"(r) : "v"(a), "v"(b));
  return r;
}
DI float fromlo(unsigned int u) { return __builtin_bit_cast(float, u << 16); }
DI float fromhi(unsigned int u) { return __builtin_bit_cast(float, u & 0xffff0000u); }

// 8 contiguous elements -> hi row + lo row, one ds_write_b128 each (bank-uniform)
DI void write_pair8(unsigned short* hp, unsigned short* lp, float4 a, float4 b) {
  unsigned int h01 = cvtpk(a.x, a.y), h23 = cvtpk(a.z, a.w);
  unsigned int h45 = cvtpk(b.x, b.y), h67 = cvtpk(b.z, b.w);
  unsigned int l01 = cvtpk(a.x - fromlo(h01), a.y - fromhi(h01));
  unsigned int l23 = cvtpk(a.z - fromlo(h23), a.w - fromhi(h23));
  unsigned int l45 = cvtpk(b.x - fromlo(h45), b.y - fromhi(h45));
  unsigned int l67 = cvtpk(b.z - fromlo(h67), b.w - fromhi(h67));
  uint4 H4; H4.x = h01; H4.y = h23; H4.z = h45; H4.w = h67;
  uint4 L4; L4.x = l01; L4.y = l23; L4.z = l45; L4.w = l67;
  *(uint4*)hp = H4;
  *(uint4*)lp = L4;
}

// fast gates: v_exp_f32 + v_rcp_f32 (~3e-7 rel err; inside bf16x3 noise envelope)
DI float fsig(float x)  { return __builtin_amdgcn_rcpf(1.f + __expf(-x)); }
DI float ftanhf(float x){ return 1.f - 2.f * __builtin_amdgcn_rcpf(1.f + __expf(2.f * x)); }

// ---------------------------------------------------------------------------
// Split-K bf16x3 GEMM, 128x128 tiles, double-buffered LDS (1 barrier/iter),
// 2-DEEP register prefetch: loadit(it+3) issued each iter, stage(it+1) waits
// only the older 8 loads (compiler emits counted vmcnt(8), not a drain).
// Buffer parity is compile-time (Ic<P>) so ra/rb stay in registers (rule #20).
// Per-acc MFMA order unchanged -> bit-exact vs previous version.
// ---------------------------------------------------------------------------
template<int M, int N, int K, int KS, bool SWZ>
__global__ __launch_bounds__(256, 2) void k_gemm(const float* __restrict__ A,
                                                 const float* __restrict__ Bw,
                                                 float* __restrict__ P) {
  constexpr int MT = M / 128, NT = N / 128;
  constexpr int KC = K / KS;
  constexpr int ITERS = KC / 32;
  static_assert(ITERS >= 4 && (ITERS % 2) == 0, "pipeline needs even ITERS>=4");
  int bid = blockIdx.x;
  int kidx, mt, nt;
  if (SWZ) {
    int xcd = bid & 7, s = bid >> 3;
    kidx = xcd + 8 * (s >> 4);
    int mn = s & 15; mt = mn >> 3; nt = mn & 7;
  } else {
    kidx = bid / (MT * NT);
    int mn = bid % (MT * NT);
    mt = mn / NT; nt = mn % NT;
  }
  int tid = threadIdx.x;
  int w = tid >> 6, lane = tid & 63, q = lane >> 4, l15 = lane & 15;
  int wm = w >> 1, wn = w & 1;

  __shared__ unsigned short Ah[2][4][128][8], Al[2][4][128][8];
  __shared__ unsigned short Bh[2][4][128][8], Bl[2][4][128][8];

  int srow = tid >> 1;
  int skb  = (tid & 1) * 16;
  const float* Abase = A  + (size_t)(mt * 128 + srow) * K + (size_t)kidx * KC;
  const float* Bbase = Bw + (size_t)(nt * 128 + srow) * K + (size_t)kidx * KC;

  float4 ra[2][4], rb[2][4];
  auto loadit = [&](int it, auto pc) {
    constexpr int BP = decltype(pc)::value;
    const float* pa = Abase + it * 32 + skb;
    const float* pb = Bbase + it * 32 + skb;
#pragma unroll
    for (int i = 0; i < 4; i++) {
      ra[BP][i] = *(const float4*)(pa + 4 * i);
      rb[BP][i] = *(const float4*)(pb + 4 * i);
    }
  };
  auto stage = [&](auto pc) {
    constexpr int PB = decltype(pc)::value;
    int qq0 = skb >> 3;  // 0 or 2
    write_pair8(&Ah[PB][qq0][srow][0],     &Al[PB][qq0][srow][0],     ra[PB][0], ra[PB][1]);
    write_pair8(&Ah[PB][qq0 + 1][srow][0], &Al[PB][qq0 + 1][srow][0], ra[PB][2], ra[PB][3]);
    write_pair8(&Bh[PB][qq0][srow][0],     &Bl[PB][qq0][srow][0],     rb[PB][0], rb[PB][1]);
    write_pair8(&Bh[PB][qq0 + 1][srow][0], &Bl[PB][qq0 + 1][srow][0], rb[PB][2], rb[PB][3]);
  };

  f32x4 acc[4][4];
#pragma unroll
  for (int i = 0; i < 4; i++)
#pragma unroll
    for (int j = 0; j < 4; j++) acc[i][j] = (f32x4){0.f, 0.f, 0.f, 0.f};

  // prologue: tiles 0,1,2 in flight; LDS[0] staged with tile 0
  loadit(0, Ic<0>{});
  stage(Ic<0>{});
  loadit(1, Ic<1>{});
  loadit(2, Ic<0>{});

  auto body = [&](int it, auto pc) {
    constexpr int Pp = decltype(pc)::value;   // read parity = it&1
    __syncthreads();
    // fragment reads first: max lead time before MFMA; staging VALU hides under
    s16x8 afh[4], afl[4], bfh[4], bfl[4];
#pragma unroll
    for (int t = 0; t < 4; t++) {
      int m = wm * 64 + 16 * t + l15;
      afh[t] = *(const s16x8*)&Ah[Pp][q][m][0];
      afl[t] = *(const s16x8*)&Al[Pp][q][m][0];
      int n = wn * 64 + 16 * t + l15;
      bfh[t] = *(const s16x8*)&Bh[Pp][q][n][0];
      bfl[t] = *(const s16x8*)&Bl[Pp][q][n][0];
    }
    // stage tile it+1 into LDS[P^1] from ra[P^1] (waits only its own 8 loads)
    if (it + 1 < ITERS) stage(Ic<Pp ^ 1>{});
    // issue tile it+3 into the register buffer just consumed
    if (it + 3 < ITERS) loadit(it + 3, Ic<Pp ^ 1>{});
    // pass 1: hh
#pragma unroll
    for (int ti = 0; ti < 4; ti++)
#pragma unroll
      for (int tj = 0; tj < 4; tj++)
        acc[ti][tj] = mfma16(afh[ti], bfh[tj], acc[ti][tj]);
    // pass 2: lh
#pragma unroll
    for (int ti = 0; ti < 4; ti++)
#pragma unroll
      for (int tj = 0; tj < 4; tj++)
        acc[ti][tj] = mfma16(afl[ti], bfh[tj], acc[ti][tj]);
    // pass 3: hl
#pragma unroll
    for (int ti = 0; ti < 4; ti++)
#pragma unroll
      for (int tj = 0; tj < 4; tj++)
        acc[ti][tj] = mfma16(afh[ti], bfl[tj], acc[ti][tj]);
  };

  for (int it = 0; it < ITERS; it += 2) {
    body(it, Ic<0>{});
    body(it + 1, Ic<1>{});
  }

#pragma unroll
  for (int ti = 0; ti < 4; ti++)
#pragma unroll
    for (int tj = 0; tj < 4; tj++)
#pragma unroll
      for (int r = 0; r < 4; r++) {
        int row = mt * 128 + wm * 64 + 16 * ti + 4 * q + r;
        int col = nt * 128 + wn * 64 + 16 * tj + l15;
        P[((size_t)kidx * M + row) * N + col] = acc[ti][tj][r];
      }
}

// ---------------------------------------------------------------------------
template<int KS>
__global__ __launch_bounds__(256) void k_red(const float* __restrict__ P,
                                             float* __restrict__ O) {
  int idx = blockIdx.x * 256 + threadIdx.x;
  float s = 0.f;
#pragma unroll
  for (int kk = 0; kk < KS; kk++) s += P[(size_t)kk * 262144 + idx];
  O[idx] = s;
}

// ---------------------------------------------------------------------------
template<int KS, int N>
__global__ __launch_bounds__(256) void k_bn(const float* __restrict__ P,
                                            const float* __restrict__ g,
                                            const float* __restrict__ be,
                                            float* __restrict__ a) {
  int tid = threadIdx.x;
  int c = tid & 15, bg = tid >> 4;
  int col = blockIdx.x * 16 + c;
  __shared__ float hbuf[256][16];
  __shared__ float sbuf[16][16], s2buf[16][16];
  __shared__ float msc[16], msh[16];
  float s = 0.f, s2 = 0.f;
  for (int b = bg * 16; b < bg * 16 + 16; b++) {
    float h = 0.f;
#pragma unroll
    for (int kk = 0; kk < KS; kk++) h += P[((size_t)kk * 256 + b) * N + col];
    hbuf[b][c] = h;
    s += h; s2 += h * h;
  }
  sbuf[bg][c] = s; s2buf[bg][c] = s2;
  __syncthreads();
  if (bg == 0) {
    float ts = 0.f, ts2 = 0.f;
#pragma unroll
    for (int i = 0; i < 16; i++) { ts += sbuf[i][c]; ts2 += s2buf[i][c]; }
    float m = ts * (1.f / 256.f);
    float v = ts2 * (1.f / 256.f) - m * m;
    float rs = rsqrtf(v + 1e-5f);
    float sc = g[col] * rs;
    msc[c] = sc;
    msh[c] = be[col] - m * sc;
  }
  __syncthreads();
  float sc = msc[c], sh = msh[c];
  for (int b = bg * 16; b < bg * 16 + 16; b++) {
    float v = hbuf[b][c] * sc + sh;
    a[(size_t)b * N + col] = v > 0.f ? v : 0.01f * v;
  }
}

// ---------------------------------------------------------------------------
__global__ __launch_bounds__(128) void k_head(const float* __restrict__ P3,
    const float* __restrict__ bout,
    const float* __restrict__ Wmu, const float* __restrict__ bmu,
    const float* __restrict__ Wlv, const float* __restrict__ blv,
    const float* __restrict__ Wih, const float* __restrict__ bih,
    const float* __restrict__ eps,
    float* __restrict__ out_mu, float* __restrict__ out_lv,
    float* __restrict__ xp) {
  int b = blockIdx.x, j = threadIdx.x;
  __shared__ float es[128], zs[128];
  float e = P3[(size_t)b * 128 + j] + P3[(size_t)(256 + b) * 128 + j] + bout[j];
  es[j] = e > 0.f ? e : 0.f;
  __syncthreads();
  float mu = bmu[j], lv = blv[j];
  for (int k = 0; k < 128; k++) {
    mu += es[k] * Wmu[j * 128 + k];
    lv += es[k] * Wlv[j * 128 + k];
  }
  out_mu[b * 128 + j] = mu;
  out_lv[b * 128 + j] = lv;
  float z = mu + eps[b * 128 + j] * expf(0.5f * lv);
  zs[j] = z;
  __syncthreads();
  for (int gi = 0; gi < 3; gi++) {
    int row = gi * 128 + j;
    float s = bih[row];
    for (int k = 0; k < 128; k++) s += zs[k] * Wih[row * 128 + k];
    xp[(size_t)b * 384 + row] = s;
  }
}

// ---------------------------------------------------------------------------
// GRU recurrence: 16 blocks x 16 batch, 512 threads (8 waves = 2 waves/SIMD).
// Each wave owns 3 gate tiles; Whh bf16x3 frags resident in VGPRs; ping-pong
// h2 LDS; 9-slot LDS h ring -> one coalesced H burst per 8 steps. MFMA loop
// kt-outer (acc revisit distance 9). h2 split via v_cvt_pk_bf16_f32.
// ---------------------------------------------------------------------------
__global__ __launch_bounds__(512, 2) void k_gru(const float* __restrict__ Whh,
    const float* __restrict__ bhh, const float* __restrict__ xp,
    float* __restrict__ H) {
  int b0 = blockIdx.x * 16;
  int tid = threadIdx.x;
  int w = tid >> 6, lane = tid & 63, q = lane >> 4, l15 = lane & 15;
  __shared__ unsigned short h2hi[2][16][136], h2lo[2][16][136];
  __shared__ float hstage[9][16][132];
  (void)lane;

  int rb3[3];
  rb3[0] = 16 * w;        // r-gate rows
  rb3[1] = 128 + 16 * w;  // z-gate rows
  rb3[2] = 256 + 16 * w;  // n-gate rows

  // weight fragments (A-operand: m=l15 row-in-tile, k = kt*32 + q*8 + j)
  s16x8 wfh[3][4], wfl[3][4];
#pragma unroll
  for (int t = 0; t < 3; t++)
#pragma unroll
    for (int kt = 0; kt < 4; kt++) {
      const float* p = Whh + (size_t)(rb3[t] + l15) * 128 + kt * 32 + q * 8;
      s16x8 hi, lo;
#pragma unroll
      for (int j = 0; j < 8; j++) {
        unsigned short h, l; split2(p[j], h, l);
        hi[j] = (short)h; lo[j] = (short)l;
      }
      wfh[t][kt] = hi; wfl[t][kt] = lo;
    }

  int gb = b0 + l15;
  int k0 = 16 * w + 4 * q;  // this thread's hid base (+r)
  float xr_[4], xz_[4], xn_[4], bhn_[4], hprev[4];
#pragma unroll
  for (int r = 0; r < 4; r++) {
    int kk = k0 + r;
    xr_[r] = xp[(size_t)gb * 384 + kk] + bhh[kk];
    xz_[r] = xp[(size_t)gb * 384 + 128 + kk] + bhh[128 + kk];
    xn_[r] = xp[(size_t)gb * 384 + 256 + kk];
    bhn_[r] = bhh[256 + kk];
    hprev[r] = 0.f;
  }

  for (int i = tid; i < 16 * 136; i += 512) {
    (&h2hi[0][0][0])[i] = 0;
    (&h2lo[0][0][0])[i] = 0;
  }
  __syncthreads();

  int hrow = tid >> 5, hcol = (tid & 31) * 4;
  int sl = 0;  // == s % 9

  for (int s = 0; s < 128; s++) {
    int p = s & 1;
    // B-frags for step s (prev h2), issued first
    s16x8 bhf[4], blf[4];
#pragma unroll
    for (int kt = 0; kt < 4; kt++) {
      bhf[kt] = *(const s16x8*)&h2hi[p][l15][kt * 32 + q * 8];
      blf[kt] = *(const s16x8*)&h2lo[p][l15][kt * 32 + q * 8];
    }
    // burst-flush previous 8 steps' h (overlaps B-frag latency + MFMA)
    if ((s & 7) == 0 && s) {
      int fb = s - 8;
#pragma unroll
      for (int ss = 0; ss < 8; ss++) {
        int t9 = sl + 1 + ss;           // (fb+ss) % 9
        int fsl = t9 >= 9 ? t9 - 9 : t9;
        float4 v = *(const float4*)&hstage[fsl][hrow][hcol];
        *(float4*)(H + ((size_t)(b0 + hrow) * 128 + fb + ss) * 128 + hcol) = v;
      }
    }

    // 6 independent MFMA chains, kt-outer (acc revisit distance 9)
    f32x4 accm[3], accc[3];
#pragma unroll
    for (int t = 0; t < 3; t++) {
      accm[t] = (f32x4){0.f, 0.f, 0.f, 0.f};
      accc[t] = (f32x4){0.f, 0.f, 0.f, 0.f};
    }
#pragma unroll
    for (int kt = 0; kt < 4; kt++) {
#pragma unroll
      for (int t = 0; t < 3; t++) accm[t] = mfma16(wfh[t][kt], bhf[kt], accm[t]);
#pragma unroll
      for (int t = 0; t < 3; t++) accc[t] = mfma16(wfl[t][kt], bhf[kt], accc[t]);
#pragma unroll
      for (int t = 0; t < 3; t++) accc[t] = mfma16(wfh[t][kt], blf[kt], accc[t]);
    }

    float hv[4];
#pragma unroll
    for (int r = 0; r < 4; r++) {
      float hr = accm[0][r] + accc[0][r];
      float hz = accm[1][r] + accc[1][r];
      float hn = accm[2][r] + accc[2][r];
      float rg = fsig(xr_[r] + hr);
      float zg = fsig(xz_[r] + hz);
      float ng = ftanhf(fmaf(rg, hn + bhn_[r], xn_[r]));
      float h2 = fmaf(zg, hprev[r] - ng, ng);
      hprev[r] = h2;
      hv[r] = h2;
    }
    unsigned int h01 = cvtpk(hv[0], hv[1]), h23 = cvtpk(hv[2], hv[3]);
    unsigned int l01 = cvtpk(hv[0] - fromlo(h01), hv[1] - fromhi(h01));
    unsigned int l23 = cvtpk(hv[2] - fromlo(h23), hv[3] - fromhi(h23));
    *(float4*)&hstage[sl][l15][k0] = make_float4(hv[0], hv[1], hv[2], hv[3]);
    uint2 hh; hh.x = h01; hh.y = h23;
    uint2 ll; ll.x = l01; ll.y = l23;
    *(uint2*)&h2hi[p ^ 1][l15][k0] = hh;
    *(uint2*)&h2lo[p ^ 1][l15][k0] = ll;
    sl = (sl == 8) ? 0 : sl + 1;
    __syncthreads();
  }
  // final flush: steps 120..127
#pragma unroll
  for (int ss = 0; ss < 8; ss++) {
    int fb = 120 + ss;
    int fsl = fb % 9;
    float4 v = *(const float4*)&hstage[fsl][hrow][hcol];
    *(float4*)(H + ((size_t)(b0 + hrow) * 128 + fb) * 128 + hcol) = v;
  }
}

// ---------------------------------------------------------------------------
// Phase B: logits = H @ Wfc^T + bfc, argmax (first-index), one-hot
// ---------------------------------------------------------------------------
__global__ __launch_bounds__(256, 2) void k_fc(const float* __restrict__ H,
    const float* __restrict__ Wfc, const float* __restrict__ bfc,
    float* __restrict__ out) {
  int rows0 = blockIdx.x * 64;
  int tid = threadIdx.x;
  int w = tid >> 6, lane = tid & 63, q = lane >> 4, l15 = lane & 15;
  __shared__ unsigned short Ah[4][4][64][8], Al[4][4][64][8];
  __shared__ unsigned short Bh[4][4][32][8], Bl[4][4][32][8];
  __shared__ int argbuf[64];
  (void)lane;

  {
    int row = tid >> 2, kb = (tid & 3) * 32;
    const float* p = H + (size_t)(rows0 + row) * 128 + kb;
    int kt = kb >> 5;
    float4 v[8];
#pragma unroll
    for (int i = 0; i < 8; i++) v[i] = *(const float4*)(p + 4 * i);
#pragma unroll
    for (int j = 0; j < 4; j++)
      write_pair8(&Ah[kt][j][row][0], &Al[kt][j][row][0], v[2 * j], v[2 * j + 1]);
  }
  __syncthreads();

  s16x8 afh[4], afl[4];
#pragma unroll
  for (int kt = 0; kt < 4; kt++) {
    afh[kt] = *(const s16x8*)&Ah[kt][q][16 * w + l15][0];
    afl[kt] = *(const s16x8*)&Al[kt][q][16 * w + l15][0];
  }

  float best[4]; int bidx[4];
#pragma unroll
  for (int r = 0; r < 4; r++) { best[r] = -3.4e38f; bidx[r] = 0; }

  for (int c = 0; c < 16; c++) {
    {
      int n = tid >> 3, kb = (tid & 7) * 16;
      const float* p = Wfc + (size_t)(c * 32 + n) * 128 + kb;
      int kt = kb >> 5, qq0 = (kb >> 3) & 3;  // qq0 in {0,2}
      float4 v0 = *(const float4*)(p);
      float4 v1 = *(const float4*)(p + 4);
      float4 v2 = *(const float4*)(p + 8);
      float4 v3 = *(const float4*)(p + 12);
      write_pair8(&Bh[kt][qq0][n][0],     &Bl[kt][qq0][n][0],     v0, v1);
      write_pair8(&Bh[kt][qq0 + 1][n][0], &Bl[kt][qq0 + 1][n][0], v2, v3);
    }
    __syncthreads();
    f32x4 acc[2];
    acc[0] = (f32x4){0.f, 0.f, 0.f, 0.f};
    acc[1] = (f32x4){0.f, 0.f, 0.f, 0.f};
    s16x8 bh[2][4], bl[2][4];
#pragma unroll
    for (int nt = 0; nt < 2; nt++)
#pragma unroll
      for (int kt = 0; kt < 4; kt++) {
        bh[nt][kt] = *(const s16x8*)&Bh[kt][q][nt * 16 + l15][0];
        bl[nt][kt] = *(const s16x8*)&Bl[kt][q][nt * 16 + l15][0];
      }
#pragma unroll
    for (int kt = 0; kt < 4; kt++)
#pragma unroll
      for (int nt = 0; nt < 2; nt++) {
        acc[nt] = mfma16(afh[kt], bh[nt][kt], acc[nt]);
        acc[nt] = mfma16(afl[kt], bh[nt][kt], acc[nt]);
        acc[nt] = mfma16(afh[kt], bl[nt][kt], acc[nt]);
      }
#pragma unroll
    for (int nt = 0; nt < 2; nt++)
#pragma unroll
      for (int r = 0; r < 4; r++) {
        int col = c * 32 + nt * 16 + l15;
        float v = acc[nt][r] + bfc[col];
        if (v > best[r]) { best[r] = v; bidx[r] = col; }
      }
    __syncthreads();
  }

#pragma unroll
  for (int r = 0; r < 4; r++) {
    float bv = best[r]; int bi = bidx[r];
    for (int off = 8; off >= 1; off >>= 1) {
      float ov = __shfl_xor(bv, off, 64);
      int oi = __shfl_xor(bi, off, 64);
      if (ov > bv || (ov == bv && oi < bi)) { bv = ov; bi = oi; }
    }
    if (l15 == 0) argbuf[16 * w + 4 * q + r] = bi;
  }
  __syncthreads();

  int row = tid >> 2, cb = (tid & 3) * 128;
  int am = argbuf[row];
  float* op = out + (size_t)(rows0 + row) * 512 + cb;
#pragma unroll
  for (int i = 0; i < 32; i++) {
    float4 v = {0.f, 0.f, 0.f, 0.f};
    int base = cb + 4 * i;
    if (am >= base && am < base + 4) ((float*)&v)[am - base] = 1.0f;
    *(float4*)(op + 4 * i) = v;
  }
}

// ---------------------------------------------------------------------------
extern "C" void kernel_launch(void* const* d_in, const int* in_sizes, int n_in,
                              void* d_out, int out_size, void* d_ws, size_t ws_size,
                              hipStream_t stream) {
  const float* x    = (const float*)d_in[0];
  const float* eps  = (const float*)d_in[1];
  const float* W0   = (const float*)d_in[2];
  const float* g0   = (const float*)d_in[4];
  const float* be0  = (const float*)d_in[5];
  const float* W1   = (const float*)d_in[6];
  const float* g1   = (const float*)d_in[8];
  const float* be1  = (const float*)d_in[9];
  const float* W2   = (const float*)d_in[10];
  const float* g2   = (const float*)d_in[12];
  const float* be2  = (const float*)d_in[13];
  const float* Wout = (const float*)d_in[14];
  const float* bout = (const float*)d_in[15];
  const float* Wmu  = (const float*)d_in[16];
  const float* bmu  = (const float*)d_in[17];
  const float* Wlv  = (const float*)d_in[18];
  const float* blv  = (const float*)d_in[19];
  const float* Wih  = (const float*)d_in[20];
  const float* bih  = (const float*)d_in[21];
  const float* Whh  = (const float*)d_in[22];
  const float* bhh  = (const float*)d_in[23];
  const float* Wfc  = (const float*)d_in[24];
  const float* bfc  = (const float*)d_in[25];

  float* out    = (float*)d_out;
  float* mu_out = out + 16777216;
  float* lv_out = out + 16777216 + 32768;

  const bool big = ws_size >= 75900000ull;
  const int KS0 = big ? 64 : 16;

  float* ws  = (float*)d_ws;
  float* P0  = ws;
  float* O0  = ws + (size_t)262144 * KS0;
  float* a1  = O0 + 262144;
  float* P1  = a1 + 262144;
  float* a2  = P1 + 1048576;
  float* P2  = a2 + 131072;
  float* a3  = P2 + 262144;
  float* P3  = a3 + 65536;
  float* xp  = P3 + 65536;
  float* Hst = ws;  // aliases P0 (dead after k_red)

  if (big) {
    hipLaunchKernelGGL((k_gemm<256,1024,65536,64,true>), dim3(1024), dim3(256), 0, stream, x, W0, P0);
    hipLaunchKernelGGL((k_red<64>),                      dim3(1024), dim3(256), 0, stream, P0, O0);
  } else {
    hipLaunchKernelGGL((k_gemm<256,1024,65536,16,true>), dim3(256),  dim3(256), 0, stream, x, W0, P0);
    hipLaunchKernelGGL((k_red<16>),                      dim3(1024), dim3(256), 0, stream, P0, O0);
  }
  hipLaunchKernelGGL((k_bn<1,1024>),                   dim3(64),  dim3(256), 0, stream, O0, g0, be0, a1);
  hipLaunchKernelGGL((k_gemm<256,512,1024,8,false>),   dim3(64),  dim3(256), 0, stream, a1, W1, P1);
  hipLaunchKernelGGL((k_bn<8,512>),                    dim3(32),  dim3(256), 0, stream, P1, g1, be1, a2);
  hipLaunchKernelGGL((k_gemm<256,256,512,4,false>),    dim3(16),  dim3(256), 0, stream, a2, W2, P2);
  hipLaunchKernelGGL((k_bn<4,256>),                    dim3(16),  dim3(256), 0, stream, P2, g2, be2, a3);
  hipLaunchKernelGGL((k_gemm<256,128,256,2,false>),    dim3(4),   dim3(256), 0, stream, a3, Wout, P3);
  hipLaunchKernelGGL(k_head, dim3(256), dim3(128), 0, stream, P3, bout, Wmu, bmu, Wlv, blv, Wih, bih, eps, mu_out, lv_out, xp);
  hipLaunchKernelGGL(k_gru,  dim3(16),  dim3(512), 0, stream, Whh, bhh, xp, Hst);
  hipLaunchKernelGGL(k_fc,   dim3(512), dim3(256), 0, stream, Hst, Wfc, bfc, out);
}